// Round 1
// baseline (887.862 us; speedup 1.0000x reference)
//
#include <hip/hip_runtime.h>
#include <math.h>

#define NN 50000
#define NE 400000
#define FDIM 128

constexpr float INV_SCALE = 0.17677669529663687f; // 1/sqrt(32)
constexpr float LN_EPS = 1e-5f;

typedef short bf16x8 __attribute__((ext_vector_type(8)));
typedef float f32x4 __attribute__((ext_vector_type(4)));

static __device__ __forceinline__ short f2bf(float f) {
    unsigned u = __builtin_bit_cast(unsigned, f);
    u += 0x7FFFu + ((u >> 16) & 1u);   // RNE
    return (short)(u >> 16);
}

// Stage a 64 x 128 f32 tile from global into LDS as bf16, XOR-swizzled.
// Swizzle: 16B chunk index c (k/8) stored at c ^ (row & 7)  -> conflict-free ds_read_b128.
static __device__ __forceinline__ void stage_tile(const float* __restrict__ gsrc,
                                                  short* At, int limit, int m0, int tid) {
#pragma unroll
    for (int j = 0; j < 4; ++j) {
        int row = (tid >> 4) + j * 16;
        int g   = tid & 15;
        int m   = m0 + row;
        float4 a0 = make_float4(0.f, 0.f, 0.f, 0.f);
        float4 a1 = make_float4(0.f, 0.f, 0.f, 0.f);
        if (m < limit) {
            const float4* p = (const float4*)(gsrc + (size_t)m * FDIM + g * 8);
            a0 = p[0];
            a1 = p[1];
        }
        bf16x8 h;
        h[0] = f2bf(a0.x); h[1] = f2bf(a0.y); h[2] = f2bf(a0.z); h[3] = f2bf(a0.w);
        h[4] = f2bf(a1.x); h[5] = f2bf(a1.y); h[6] = f2bf(a1.z); h[7] = f2bf(a1.w);
        *(bf16x8*)(At + row * FDIM + ((g ^ (row & 7)) * 8)) = h;
    }
}

// Load the 4 K-step A fragments for this wave's 16-row stripe.
// A layout (16x16x32): lane l holds A[row = l&15][k = (l>>4)*8 + i].
static __device__ __forceinline__ void load_afrags(const short* At, int w, int l, bf16x8* a) {
    int lr = l & 15, lq = l >> 4;
    int arow = w * 16 + lr;
#pragma unroll
    for (int ks = 0; ks < 4; ++ks) {
        int ch = ks * 4 + lq;
        a[ks] = *(const bf16x8*)(At + arow * FDIM + ((ch ^ (arow & 7)) * 8));
    }
}

// OUT(16x128 per wave) = A(16x128) @ W^T + bias, W row-major [128][128] bf16.
// B layout: lane l holds B[k=(l>>4)*8+i][col=l&15] = W[col][k] -> contiguous 16B along k.
static __device__ __forceinline__ void mfma_gemm(const bf16x8* a,
                                                 const short* __restrict__ W,
                                                 const float* __restrict__ bias,
                                                 int lr, int lq, f32x4* acc) {
#pragma unroll
    for (int n = 0; n < 8; ++n) {
        float bb = bias[n * 16 + lr];
        f32x4 t; t[0] = bb; t[1] = bb; t[2] = bb; t[3] = bb;
        acc[n] = t;
#pragma unroll
        for (int ks = 0; ks < 4; ++ks) {
            bf16x8 b = *(const bf16x8*)(W + (n * 16 + lr) * FDIM + ks * 32 + lq * 8);
            acc[n] = __builtin_amdgcn_mfma_f32_16x16x32_bf16(a[ks], b, acc[n], 0, 0, 0);
        }
    }
}

__global__ __launch_bounds__(256) void convert_weights(
    const float* __restrict__ w0, const float* __restrict__ w1,
    const float* __restrict__ w2, const float* __restrict__ w3,
    const float* __restrict__ w4, const float* __restrict__ w5,
    short* __restrict__ out) {
    int idx = blockIdx.x * 256 + threadIdx.x;   // 6*16384 total
    const float* srcs[6] = {w0, w1, w2, w3, w4, w5};
    out[idx] = f2bf(srcs[idx >> 14][idx & 16383]);
}

__global__ __launch_bounds__(256) void node_proj_kernel(
    const float* __restrict__ nf,
    const short* __restrict__ wq16, const short* __restrict__ wk16,
    const short* __restrict__ wv16, const short* __restrict__ wo16,
    const float* __restrict__ bq, const float* __restrict__ bk,
    const float* __restrict__ bv, const float* __restrict__ bo,
    float* __restrict__ q, float* __restrict__ k, float* __restrict__ v,
    float* __restrict__ xout) {
    __shared__ __align__(16) short At[64 * FDIM];
    int m0  = blockIdx.x * 64;
    int tid = threadIdx.x;
    stage_tile(nf, At, NN, m0, tid);
    __syncthreads();
    int w = tid >> 6, l = tid & 63;
    int lr = l & 15, lq = l >> 4;
    bf16x8 a[4];
    load_afrags(At, w, l, a);
    f32x4 acc[8];
    const short* Ws[4] = {wq16, wk16, wv16, wo16};
    const float* Bs[4] = {bq, bk, bv, bo};
    float*       Os[4] = {q, k, v, xout};
#pragma unroll
    for (int t = 0; t < 4; ++t) {
        mfma_gemm(a, Ws[t], Bs[t], lr, lq, acc);
#pragma unroll
        for (int n = 0; n < 8; ++n)
#pragma unroll
            for (int r = 0; r < 4; ++r) {
                int m = m0 + w * 16 + lq * 4 + r;
                if (m < NN) Os[t][(size_t)m * FDIM + n * 16 + lr] = acc[n][r];
            }
    }
}

__global__ __launch_bounds__(256) void edge_kernel(
    const float* __restrict__ ef, const int* __restrict__ src, const int* __restrict__ dst,
    const short* __restrict__ we16, const short* __restrict__ wev16,
    const float* __restrict__ be, const float* __restrict__ bev,
    const float* __restrict__ q, const float* __restrict__ k, const float* __restrict__ v,
    const float* __restrict__ ln_eg, const float* __restrict__ ln_eb,
    float* __restrict__ agg, float* __restrict__ yout) {
    __shared__ __align__(16) short At[64 * FDIM];
    __shared__ __align__(16) float sc[64 * 4];   // [edge-in-tile][head], score/sqrt(C)
    int e0  = blockIdx.x * 64;
    int tid = threadIdx.x;
    stage_tile(ef, At, NE, e0, tid);             // E % 64 == 0, guard never fires

    int w = tid >> 6, l = tid & 63;
    {   // scores: each lane = one (edge, head) of this wave's 16 edges
        int eidx = w * 16 + (l >> 2);
        int h    = l & 3;
        int eg   = e0 + eidx;
        int se = src[eg], de = dst[eg];
        const float4* qp = (const float4*)(q + (size_t)se * FDIM + h * 32);
        const float4* kp = (const float4*)(k + (size_t)de * FDIM + h * 32);
        float s = 0.f;
#pragma unroll
        for (int i = 0; i < 8; ++i) {
            float4 qa = qp[i], ka = kp[i];
            s += qa.x * ka.x + qa.y * ka.y + qa.z * ka.z + qa.w * ka.w;
        }
        sc[eidx * 4 + h] = s * INV_SCALE;
    }
    __syncthreads();

    int lr = l & 15, lq = l >> 4;
    bf16x8 a[4];
    load_afrags(At, w, l, a);
    f32x4 me[8], mvv[8];
    mfma_gemm(a, we16, be, lr, lq, me);     // m (before score add)
    mfma_gemm(a, wev16, bev, lr, lq, mvv);  // edge residual branch

    int rowb = w * 16 + lq * 4;
    float sr[4][4];
#pragma unroll
    for (int r = 0; r < 4; ++r) {
        f32x4 t = *(const f32x4*)(sc + (rowb + r) * 4);
        sr[r][0] = t[0]; sr[r][1] = t[1]; sr[r][2] = t[2]; sr[r][3] = t[3];
    }
    // m = score/SCALE + eproj ; frag n covers cols n*16..n*16+15 -> head = n>>1
#pragma unroll
    for (int n = 0; n < 8; ++n)
#pragma unroll
        for (int r = 0; r < 4; ++r)
            me[n][r] += sr[r][n >> 1];

    // softmax over the 4 heads (per fixed col-within-head), gather v[src], scatter-add agg[dst]
#pragma unroll
    for (int r = 0; r < 4; ++r) {
        int eg = e0 + rowb + r;
        int se = src[eg], de = dst[eg];
#pragma unroll
        for (int half = 0; half < 2; ++half) {
            float v0 = me[half][r],     v1 = me[half + 2][r];
            float v2 = me[half + 4][r], v3 = me[half + 6][r];
            float mx = fmaxf(fmaxf(v0, v1), fmaxf(v2, v3));
            float x0 = __expf(v0 - mx), x1 = __expf(v1 - mx);
            float x2 = __expf(v2 - mx), x3 = __expf(v3 - mx);
            float inv = 1.f / (x0 + x1 + x2 + x3);
            float at[4] = {x0 * inv, x1 * inv, x2 * inv, x3 * inv};
#pragma unroll
            for (int h = 0; h < 4; ++h) {
                int col = (2 * h + half) * 16 + lr;
                float vv = v[(size_t)se * FDIM + col];
                unsafeAtomicAdd(&agg[(size_t)de * FDIM + col], vv * at[h]);
            }
        }
    }

    // y = silu(layernorm(m)) + (edge@Wev^T + bev)
#pragma unroll
    for (int r = 0; r < 4; ++r) {
        float sum1 = 0.f, sum2 = 0.f;
#pragma unroll
        for (int n = 0; n < 8; ++n) { float t = me[n][r]; sum1 += t; sum2 += t * t; }
#pragma unroll
        for (int off = 1; off < 16; off <<= 1) {
            sum1 += __shfl_xor(sum1, off);
            sum2 += __shfl_xor(sum2, off);
        }
        float mean = sum1 * (1.f / 128.f);
        float var  = sum2 * (1.f / 128.f) - mean * mean;
        float rstd = rsqrtf(var + LN_EPS);
        int eg = e0 + rowb + r;
#pragma unroll
        for (int n = 0; n < 8; ++n) {
            int col = n * 16 + lr;
            float t  = (me[n][r] - mean) * rstd * ln_eg[col] + ln_eb[col];
            float si = t / (1.f + __expf(-t));
            yout[(size_t)eg * FDIM + col] = si + mvv[n][r];
        }
    }
}

__global__ __launch_bounds__(256) void node_epilogue(
    const float* __restrict__ agg,
    const float* __restrict__ ln_ng, const float* __restrict__ ln_nb,
    float* __restrict__ xout) {
    int row = blockIdx.x * 4 + (threadIdx.x >> 6);
    if (row >= NN) return;
    int l = threadIdx.x & 63;
    float2 aa = *(const float2*)(agg + (size_t)row * FDIM + l * 2);
    float sum1 = aa.x + aa.y, sum2 = aa.x * aa.x + aa.y * aa.y;
#pragma unroll
    for (int off = 1; off < 64; off <<= 1) {
        sum1 += __shfl_xor(sum1, off);
        sum2 += __shfl_xor(sum2, off);
    }
    float mean = sum1 * (1.f / 128.f);
    float var  = sum2 * (1.f / 128.f) - mean * mean;
    float rstd = rsqrtf(var + LN_EPS);
    float2 gg = *(const float2*)(ln_ng + l * 2);
    float2 bb = *(const float2*)(ln_nb + l * 2);
    float t0 = (aa.x - mean) * rstd * gg.x + bb.x;
    float t1 = (aa.y - mean) * rstd * gg.y + bb.y;
    float s0 = t0 / (1.f + __expf(-t0));
    float s1 = t1 / (1.f + __expf(-t1));
    float2 o = *(const float2*)(xout + (size_t)row * FDIM + l * 2);
    o.x += s0;
    o.y += s1;
    *(float2*)(xout + (size_t)row * FDIM + l * 2) = o;
}

extern "C" void kernel_launch(void* const* d_in, const int* in_sizes, int n_in,
                              void* d_out, int out_size, void* d_ws, size_t ws_size,
                              hipStream_t stream) {
    const float* nf   = (const float*)d_in[0];
    const float* ef   = (const float*)d_in[1];
    const int*   src  = (const int*)d_in[2];
    const int*   dst  = (const int*)d_in[3];
    const float* Wq   = (const float*)d_in[4];  const float* bq   = (const float*)d_in[5];
    const float* Wk   = (const float*)d_in[6];  const float* bk   = (const float*)d_in[7];
    const float* Wv   = (const float*)d_in[8];  const float* bv   = (const float*)d_in[9];
    const float* We   = (const float*)d_in[10]; const float* be   = (const float*)d_in[11];
    const float* Wev  = (const float*)d_in[12]; const float* bev  = (const float*)d_in[13];
    const float* Wout = (const float*)d_in[14]; const float* bout = (const float*)d_in[15];
    const float* ln_ng = (const float*)d_in[16]; const float* ln_nb = (const float*)d_in[17];
    const float* ln_eg = (const float*)d_in[18]; const float* ln_eb = (const float*)d_in[19];

    float* xout = (float*)d_out;              // [N*128]
    float* yout = xout + (size_t)NN * FDIM;   // [E*128]

    float* q   = (float*)d_ws;
    float* k   = q + (size_t)NN * FDIM;
    float* v   = k + (size_t)NN * FDIM;
    float* agg = v + (size_t)NN * FDIM;
    short* w16 = (short*)(agg + (size_t)NN * FDIM);
    short* wq16  = w16;
    short* wk16  = w16 + 16384;
    short* wv16  = w16 + 32768;
    short* we16  = w16 + 49152;
    short* wev16 = w16 + 65536;
    short* wo16  = w16 + 81920;

    hipMemsetAsync(agg, 0, (size_t)NN * FDIM * sizeof(float), stream);
    convert_weights<<<384, 256, 0, stream>>>(Wq, Wk, Wv, We, Wev, Wout, w16);
    node_proj_kernel<<<(NN + 63) / 64, 256, 0, stream>>>(
        nf, wq16, wk16, wv16, wo16, bq, bk, bv, bout, q, k, v, xout);
    edge_kernel<<<NE / 64, 256, 0, stream>>>(
        ef, src, dst, we16, wev16, be, bev, q, k, v, ln_eg, ln_eb, agg, yout);
    node_epilogue<<<(NN + 3) / 4, 256, 0, stream>>>(agg, ln_ng, ln_nb, xout);
}